// Round 1
// baseline (2646.930 us; speedup 1.0000x reference)
//
#include <hip/hip_runtime.h>

#define LX 6
#define LY 6
#define NSITE 36
#define TSZ (NSITE * 2 * 256)   // 18432 floats: transposed, zero-padded site tensors

// T table: Tt[site][s][(v + 4*l)][(v' + 4*r')] ; zero outside valid boundary dims
__device__ float g_Tt[TSZ];

__global__ __launch_bounds__(256) void build_T_kernel(const float* __restrict__ peps) {
    int idx = blockIdx.x * 256 + threadIdx.x;
    if (idx >= TSZ) return;
    int o    = idx & 15;          // v' + 4*r'
    int vl   = (idx >> 4) & 15;   // v + 4*l
    int s    = (idx >> 8) & 1;
    int site = idx >> 9;          // i*LY + j
    int i = site / LY, j = site - i * LY;
    int v = vl & 3, l = vl >> 2, vp = o & 3, rp = o >> 2;
    bool ok = (i > 0 || v == 0) && (i < LX - 1 || vp == 0) &&
              (j > 0 || l == 0) && (j < LY - 1 || rp == 0);
    // peps[i][j][s][u][d][l][r]: strides 512,256,64,16,4,1 (floats)
    g_Tt[idx] = ok ? peps[site * 512 + s * 256 + v * 64 + vp * 16 + l * 4 + rp] : 0.0f;
}

__device__ __forceinline__ void fma4(float4& a, float s, const float4& t) {
    a.x = __builtin_fmaf(s, t.x, a.x);
    a.y = __builtin_fmaf(s, t.y, a.y);
    a.z = __builtin_fmaf(s, t.z, a.z);
    a.w = __builtin_fmaf(s, t.w, a.w);
}

// env layout: flat index = v + 4*s0 + 16*s1 + 64*s2 + 256*s3 + 1024*s4 + 4096*s5
// Step (i,j): contract (v, slot_i) with T; outputs (v', r'=slot_i) land at the
// SAME 16 addresses -> in-place, one owner thread per rest-combo.
__global__ __launch_bounds__(256, 2) void peps_amp_kernel(const int* __restrict__ x,
                                                          float* __restrict__ out) {
    __shared__ float env[16384];
    const int tid = threadIdx.x;
    const int b = blockIdx.x;

    // zero-init env (garbage quarantine relies on this), then env[0] = 1
    #pragma unroll
    for (int p = 0; p < 16; ++p)
        *(float4*)&env[(tid + p * 256) * 4] = make_float4(0.f, 0.f, 0.f, 0.f);
    __syncthreads();
    if (tid == 0) env[0] = 1.0f;
    __syncthreads();

    const int* xr = x + b * NSITE;

    for (int j = 0; j < LY; ++j) {
        for (int i = 0; i < LX; ++i) {
            const int s = __builtin_amdgcn_readfirstlane(xr[i * LY + j]);
            const float* __restrict__ T = g_Tt + ((i * LY + j) * 2 + s) * 256;

            // valid rest-combo count
            int N;
            if (j == 0)           N = 1 << (2 * i);            // slots>i must be 0
            else if (j == LY - 1) N = 1 << (2 * (LX - 1 - i)); // slots<i must be 0
            else                  N = 1024;

            const int sh = 2 * i;
            const int ls = sh + 2;              // log2(stride of slot i) = log2(4^(i+1))
            const int lomask = (1 << sh) - 1;

            int baseA[4];
            #pragma unroll
            for (int k = 0; k < 4; ++k) {
                int c = tid + (k << 8);
                baseA[k] = (j == LY - 1)
                         ? (c << (sh + 4))                                  // c enumerates slots>i
                         : (((c & lomask) << 2) + ((c >> sh) << (sh + 4))); // skip slot i
            }

            float4 acc[4][4];
            #pragma unroll
            for (int k = 0; k < 4; ++k)
                #pragma unroll
                for (int r = 0; r < 4; ++r)
                    acc[k][r] = make_float4(0.f, 0.f, 0.f, 0.f);

            if (i == 0) {
                // u-dim == 1: only v = 0 contributes (T rows 4*l)
                #pragma unroll
                for (int l = 0; l < 4; ++l) {
                    const float* Trow = T + (4 * l) * 16;
                    float4 t0 = *(const float4*)(Trow + 0);
                    float4 t1 = *(const float4*)(Trow + 4);
                    float4 t2 = *(const float4*)(Trow + 8);
                    float4 t3 = *(const float4*)(Trow + 12);
                    #pragma unroll
                    for (int k = 0; k < 4; ++k) {
                        if (tid + (k << 8) < N) {
                            float iv = env[baseA[k] + (l << ls)];
                            fma4(acc[k][0], iv, t0);
                            fma4(acc[k][1], iv, t1);
                            fma4(acc[k][2], iv, t2);
                            fma4(acc[k][3], iv, t3);
                        }
                    }
                }
            } else {
                for (int l = 0; l < 4; ++l) {
                    float4 tr[4][4];
                    #pragma unroll
                    for (int v = 0; v < 4; ++v)
                        #pragma unroll
                        for (int r = 0; r < 4; ++r)
                            tr[v][r] = *(const float4*)(T + (v + 4 * l) * 16 + 4 * r);
                    #pragma unroll
                    for (int k = 0; k < 4; ++k) {
                        if (tid + (k << 8) < N) {
                            float4 iv = *(const float4*)&env[baseA[k] + (l << ls)];
                            #pragma unroll
                            for (int r = 0; r < 4; ++r) {
                                fma4(acc[k][r], iv.x, tr[0][r]);
                                fma4(acc[k][r], iv.y, tr[1][r]);
                                fma4(acc[k][r], iv.z, tr[2][r]);
                                fma4(acc[k][r], iv.w, tr[3][r]);
                            }
                        }
                    }
                }
            }

            // in-place writeback (same 16 addresses this thread read)
            #pragma unroll
            for (int k = 0; k < 4; ++k) {
                if (tid + (k << 8) < N) {
                    #pragma unroll
                    for (int r = 0; r < 4; ++r)
                        *(float4*)&env[baseA[k] + (r << ls)] = acc[k][r];
                }
            }
            __syncthreads();
        }
    }

    if (tid == 0) out[b] = env[0];
}

extern "C" void kernel_launch(void* const* d_in, const int* in_sizes, int n_in,
                              void* d_out, int out_size, void* d_ws, size_t ws_size,
                              hipStream_t stream) {
    const int* x = (const int*)d_in[0];
    const float* peps = (const float*)d_in[1];
    float* out = (float*)d_out;

    build_T_kernel<<<(TSZ + 255) / 256, 256, 0, stream>>>(peps);
    peps_amp_kernel<<<out_size, 256, 0, stream>>>(x, out);
}

// Round 2
// 1822.051 us; speedup vs baseline: 1.4527x; 1.4527x over previous
//
#include <hip/hip_runtime.h>

#define LX 6
#define LY 6
#define NSITE 36
#define TSZ (NSITE * 2 * 256)   // 18432 floats: transposed, zero-padded site tensors

// T table: Tt[site][s][(v + 4*l)][(v' + 4*r')] ; zero outside valid boundary dims
__device__ float g_Tt[TSZ];

__global__ __launch_bounds__(256) void build_T_kernel(const float* __restrict__ peps) {
    int idx = blockIdx.x * 256 + threadIdx.x;
    if (idx >= TSZ) return;
    int o    = idx & 15;          // v' + 4*r'
    int vl   = (idx >> 4) & 15;   // v + 4*l
    int s    = (idx >> 8) & 1;
    int site = idx >> 9;          // i*LY + j
    int i = site / LY, j = site - i * LY;
    int v = vl & 3, l = vl >> 2, vp = o & 3, rp = o >> 2;
    bool ok = (i > 0 || v == 0) && (i < LX - 1 || vp == 0) &&
              (j > 0 || l == 0) && (j < LY - 1 || rp == 0);
    // peps[i][j][s][u][d][l][r]: strides 512,256,64,16,4,1 (floats)
    g_Tt[idx] = ok ? peps[site * 512 + s * 256 + v * 64 + vp * 16 + l * 4 + rp] : 0.0f;
}

// Bank-conflict swizzle: bijection on [0,16384), float4-aligned.
// XORs env bits 5..7 into the bank-cluster bits 2..4 (bank = (f mod 32)).
__device__ __forceinline__ int swz(int f) {
    return f ^ (((f >> 5) & 7) << 2);
}

__device__ __forceinline__ void fma4(float4& a, float s, const float4& t) {
    a.x = __builtin_fmaf(s, t.x, a.x);
    a.y = __builtin_fmaf(s, t.y, a.y);
    a.z = __builtin_fmaf(s, t.z, a.z);
    a.w = __builtin_fmaf(s, t.w, a.w);
}

// env layout (pre-swizzle): flat = v + 4*s0 + 16*s1 + 64*s2 + 256*s3 + 1024*s4 + 4096*s5
// Step (i,j): contract (v, slot_i); outputs (v', r'=slot_i) land at the SAME 16
// addresses -> in-place, one owner thread per rest-combo. All accesses go through swz().
__global__ __launch_bounds__(512, 4) void peps_amp_kernel(const int* __restrict__ x,
                                                          float* __restrict__ out) {
    __shared__ float env[16384];
    const int tid = threadIdx.x;
    const int b = blockIdx.x;

    // zero-init env (invalid-region quarantine relies on exact zeros)
    #pragma unroll
    for (int p = 0; p < 8; ++p)
        *(float4*)&env[(tid + p * 512) * 4] = make_float4(0.f, 0.f, 0.f, 0.f);
    __syncthreads();
    if (tid == 0) env[0] = 1.0f;   // swz(0)==0
    __syncthreads();

    const int* xr = x + b * NSITE;

    #pragma unroll 1
    for (int j = 0; j < LY; ++j) {
        #pragma unroll 1
        for (int i = 0; i < LX; ++i) {
            const int s = __builtin_amdgcn_readfirstlane(xr[i * LY + j]);
            const float* __restrict__ T = g_Tt + ((i * LY + j) * 2 + s) * 256;

            // valid rest-combo count
            int N;
            if (j == 0)           N = 1 << (2 * i);            // slots>i must be 0
            else if (j == LY - 1) N = 1 << (2 * (LX - 1 - i)); // slots<i must be 0
            else                  N = 1024;

            const int sh = 2 * i;
            const int ls = sh + 2;              // log2(stride of slot i)
            const int lomask = (1 << sh) - 1;

            int baseA[2];
            bool act[2];
            #pragma unroll
            for (int k = 0; k < 2; ++k) {
                int c = tid + (k << 9);
                act[k] = (c < N);
                baseA[k] = (j == LY - 1)
                         ? (c << (sh + 4))                                  // c enumerates slots>i
                         : (((c & lomask) << 2) + ((c >> sh) << (sh + 4))); // skip slot i
            }

            float4 acc[2][4];
            #pragma unroll
            for (int k = 0; k < 2; ++k)
                #pragma unroll
                for (int r = 0; r < 4; ++r)
                    acc[k][r] = make_float4(0.f, 0.f, 0.f, 0.f);

            // Unified vectorized path. For i==0 the v!=0 env entries are exactly
            // 0.0f (zero-init + zero-padded v' rows written by the i=LX-1 step),
            // so the extra MACs contribute exact zeros.
            #pragma unroll
            for (int l = 0; l < 4; ++l) {
                float4 tr[4][4];
                #pragma unroll
                for (int v = 0; v < 4; ++v)
                    #pragma unroll
                    for (int r = 0; r < 4; ++r)
                        tr[v][r] = *(const float4*)(T + (v + 4 * l) * 16 + 4 * r);
                #pragma unroll
                for (int k = 0; k < 2; ++k) {
                    if (act[k]) {
                        float4 iv = *(const float4*)&env[swz(baseA[k] + (l << ls))];
                        #pragma unroll
                        for (int r = 0; r < 4; ++r) {
                            fma4(acc[k][r], iv.x, tr[0][r]);
                            fma4(acc[k][r], iv.y, tr[1][r]);
                            fma4(acc[k][r], iv.z, tr[2][r]);
                            fma4(acc[k][r], iv.w, tr[3][r]);
                        }
                    }
                }
            }

            // in-place writeback (same 16 swizzled addresses this thread read)
            #pragma unroll
            for (int k = 0; k < 2; ++k) {
                if (act[k]) {
                    #pragma unroll
                    for (int r = 0; r < 4; ++r)
                        *(float4*)&env[swz(baseA[k] + (r << ls))] = acc[k][r];
                }
            }
            __syncthreads();
        }
    }

    if (tid == 0) out[b] = env[0];
}

extern "C" void kernel_launch(void* const* d_in, const int* in_sizes, int n_in,
                              void* d_out, int out_size, void* d_ws, size_t ws_size,
                              hipStream_t stream) {
    const int* x = (const int*)d_in[0];
    const float* peps = (const float*)d_in[1];
    float* out = (float*)d_out;

    build_T_kernel<<<(TSZ + 255) / 256, 256, 0, stream>>>(peps);
    peps_amp_kernel<<<out_size, 512, 0, stream>>>(x, out);
}

// Round 3
// 1113.797 us; speedup vs baseline: 2.3765x; 1.6359x over previous
//
#include <hip/hip_runtime.h>

#define LX 6
#define LY 6
#define NSITE 36
#define TSZ (NSITE * 2 * 256)   // transposed, zero-padded site tensors

// T table: Tt[site][s][(v + 4*l)][(v' + 4*r')] ; zero outside valid boundary dims
__device__ float g_Tt[TSZ];

__global__ __launch_bounds__(256) void build_T_kernel(const float* __restrict__ peps) {
    int idx = blockIdx.x * 256 + threadIdx.x;
    if (idx >= TSZ) return;
    int o    = idx & 15;          // v' + 4*r'
    int vl   = (idx >> 4) & 15;   // v + 4*l
    int s    = (idx >> 8) & 1;
    int site = idx >> 9;          // i*LY + j
    int i = site / LY, j = site - i * LY;
    int v = vl & 3, l = vl >> 2, vp = o & 3, rp = o >> 2;
    bool ok = (i > 0 || v == 0) && (i < LX - 1 || vp == 0) &&
              (j > 0 || l == 0) && (j < LY - 1 || rp == 0);
    // peps[i][j][s][u][d][l][r]: strides 512,256,64,16,4,1 (floats)
    g_Tt[idx] = ok ? peps[site * 512 + s * 256 + v * 64 + vp * 16 + l * 4 + rp] : 0.0f;
}

// Bank swizzle: bijection, float4-aligned; XOR bits 5..7 and 8..10 into cluster bits 2..4.
// Gives <=2-way clusters for the fused access patterns (base strides 64t / 4lo+1024hi / 4t).
__device__ __forceinline__ int swz(int f) {
    return f ^ ((((f >> 5) ^ (f >> 8)) & 7) << 2);
}

__device__ __forceinline__ void fma4(float4& a, float s, const float4& t) {
    a.x = __builtin_fmaf(s, t.x, a.x);
    a.y = __builtin_fmaf(s, t.y, a.y);
    a.z = __builtin_fmaf(s, t.z, a.z);
    a.w = __builtin_fmaf(s, t.w, a.w);
}

__device__ __forceinline__ float f4c(const float4& v, int i) {
    return i == 0 ? v.x : i == 1 ? v.y : i == 2 ? v.z : v.w;
}

// Fused pair of row-steps (I, I+1) for one column.
// env flat (pre-swizzle) = v + 4*s0 + 16*s1 + 64*s2 + 256*s3 + 1024*s4 + 4096*s5.
// a = slot I (stride S1), b = slot I+1 (stride S2); thread owns one rest-combo.
// TOPB: site(I,col) has u-dim 1 -> only v=0 input row. BOTB: site(I+1,col) has
// d-dim 1 -> only v''=0 output (rest written as exact 0 to keep quarantine).
template<int I, bool TOPB, bool BOTB>
__device__ __forceinline__ void fused_pair(float* env, const float* __restrict__ T1,
                                           const float* __restrict__ T2, int tid) {
    constexpr int S1 = 1 << (2 * I + 2);
    constexpr int S2 = S1 << 2;
    const int lo = tid & ((1 << (2 * I)) - 1);
    const int hi = tid >> (2 * I);
    const int base = 4 * lo + (hi << (2 * I + 6));

    float4 inter[4][4];   // [a'][b], components = v'
    #pragma unroll
    for (int ap = 0; ap < 4; ++ap)
        #pragma unroll
        for (int bb = 0; bb < 4; ++bb)
            inter[ap][bb] = make_float4(0.f, 0.f, 0.f, 0.f);

    // ---- stage 1: inter[v'][a'][b] = sum_{v,a} in[v][a][b] * T1[(v,a),(v',a')] ----
    if (TOPB) {
        #pragma unroll
        for (int a = 0; a < 4; ++a) {
            float in0[4];
            #pragma unroll
            for (int bb = 0; bb < 4; ++bb)
                in0[bb] = env[swz(base + a * S1 + bb * S2)];
            #pragma unroll
            for (int ap = 0; ap < 4; ++ap) {
                float4 t1 = *(const float4*)(T1 + (4 * a) * 16 + 4 * ap);   // v = 0 row
                #pragma unroll
                for (int bb = 0; bb < 4; ++bb)
                    fma4(inter[ap][bb], in0[bb], t1);
            }
        }
    } else {
        #pragma unroll
        for (int a = 0; a < 4; ++a) {
            float4 inv[4];
            #pragma unroll
            for (int bb = 0; bb < 4; ++bb)
                inv[bb] = *(const float4*)&env[swz(base + a * S1 + bb * S2)];
            #pragma unroll
            for (int v = 0; v < 4; ++v) {
                #pragma unroll
                for (int ap = 0; ap < 4; ++ap) {
                    float4 t1 = *(const float4*)(T1 + (v + 4 * a) * 16 + 4 * ap);
                    #pragma unroll
                    for (int bb = 0; bb < 4; ++bb)
                        fma4(inter[ap][bb], f4c(inv[bb], v), t1);
                }
            }
        }
    }

    // ---- stage 2: out[v''][a'][b'] = sum_{v',b} inter[v'][a'][b] * T2[(v',b),(v'',b')] ----
    #pragma unroll
    for (int ap = 0; ap < 4; ++ap) {
        if (BOTB) {
            float o[4] = {0.f, 0.f, 0.f, 0.f};
            #pragma unroll
            for (int bb = 0; bb < 4; ++bb)
                #pragma unroll
                for (int vp = 0; vp < 4; ++vp) {
                    float iv = f4c(inter[ap][bb], vp);
                    #pragma unroll
                    for (int bp = 0; bp < 4; ++bp)
                        o[bp] = __builtin_fmaf(iv, T2[(vp + 4 * bb) * 16 + 4 * bp], o[bp]);
                }
            #pragma unroll
            for (int bp = 0; bp < 4; ++bp)
                *(float4*)&env[swz(base + ap * S1 + bp * S2)] = make_float4(o[bp], 0.f, 0.f, 0.f);
        } else {
            float4 outv[4];
            #pragma unroll
            for (int bp = 0; bp < 4; ++bp) outv[bp] = make_float4(0.f, 0.f, 0.f, 0.f);
            #pragma unroll
            for (int bb = 0; bb < 4; ++bb)
                #pragma unroll
                for (int vp = 0; vp < 4; ++vp) {
                    float iv = f4c(inter[ap][bb], vp);
                    #pragma unroll
                    for (int bp = 0; bp < 4; ++bp) {
                        float4 t2 = *(const float4*)(T2 + (vp + 4 * bb) * 16 + 4 * bp);
                        fma4(outv[bp], iv, t2);
                    }
                }
            #pragma unroll
            for (int bp = 0; bp < 4; ++bp)
                *(float4*)&env[swz(base + ap * S1 + bp * S2)] = outv[bp];
        }
    }
}

__global__ __launch_bounds__(256, 2) void peps_amp_kernel(const int* __restrict__ x,
                                                          float* __restrict__ out) {
    __shared__ float env[16384];
    const int tid = threadIdx.x;
    const int b = blockIdx.x;
    const int* xr = x + b * NSITE;

    // zero-init env (exact-zero quarantine for invalid regions)
    #pragma unroll
    for (int p = 0; p < 16; ++p)
        *(float4*)&env[(tid + p * 256) * 4] = make_float4(0.f, 0.f, 0.f, 0.f);
    __syncthreads();

    // ---- column 0: closed-form MPS chain -> env(r0..r5) at flat = 4*(r0+4r1+...+1024r5)
    {
        const float* A0 = g_Tt + ((0 * LY + 0) * 2 + __builtin_amdgcn_readfirstlane(xr[0 * LY])) * 256;
        const float* A1 = g_Tt + ((1 * LY + 0) * 2 + __builtin_amdgcn_readfirstlane(xr[1 * LY])) * 256;
        const float* A2 = g_Tt + ((2 * LY + 0) * 2 + __builtin_amdgcn_readfirstlane(xr[2 * LY])) * 256;
        const float* A3 = g_Tt + ((3 * LY + 0) * 2 + __builtin_amdgcn_readfirstlane(xr[3 * LY])) * 256;
        const float* A4 = g_Tt + ((4 * LY + 0) * 2 + __builtin_amdgcn_readfirstlane(xr[4 * LY])) * 256;
        const float* A5 = g_Tt + ((5 * LY + 0) * 2 + __builtin_amdgcn_readfirstlane(xr[5 * LY])) * 256;
        // A_i(r)[u][d] = T[(u + 4*0)][(d + 4r)]  (l = 0 for column 0)
        const int r2 = tid & 3, r3 = (tid >> 2) & 3, r4 = (tid >> 4) & 3, r5 = (tid >> 6) & 3;
        float w[4], w2[4];
        #pragma unroll
        for (int u = 0; u < 4; ++u) w[u] = A5[u * 16 + 4 * r5];                    // d = 0
        #pragma unroll
        for (int u = 0; u < 4; ++u) { float acc = 0;
            #pragma unroll
            for (int d = 0; d < 4; ++d) acc = __builtin_fmaf(A4[u * 16 + d + 4 * r4], w[d], acc);
            w2[u] = acc; }
        #pragma unroll
        for (int u = 0; u < 4; ++u) { float acc = 0;
            #pragma unroll
            for (int d = 0; d < 4; ++d) acc = __builtin_fmaf(A3[u * 16 + d + 4 * r3], w2[d], acc);
            w[u] = acc; }
        #pragma unroll
        for (int u = 0; u < 4; ++u) { float acc = 0;
            #pragma unroll
            for (int d = 0; d < 4; ++d) acc = __builtin_fmaf(A2[u * 16 + d + 4 * r2], w[d], acc);
            w2[u] = acc; }
        #pragma unroll
        for (int r1 = 0; r1 < 4; ++r1) {
            float u1[4];
            #pragma unroll
            for (int u = 0; u < 4; ++u) { float acc = 0;
                #pragma unroll
                for (int d = 0; d < 4; ++d) acc = __builtin_fmaf(A1[u * 16 + d + 4 * r1], w2[d], acc);
                u1[u] = acc; }
            #pragma unroll
            for (int r0 = 0; r0 < 4; ++r0) {
                float acc = 0;
                #pragma unroll
                for (int d = 0; d < 4; ++d) acc = __builtin_fmaf(A0[d + 4 * r0], u1[d], acc);
                env[swz(4 * (r0 + 4 * r1 + 16 * tid))] = acc;
            }
        }
    }
    __syncthreads();

    // ---- columns 1..4: three fused row-pairs each ----
    #pragma unroll 1
    for (int j = 1; j < LY - 1; ++j) {
        const float* T0 = g_Tt + ((0 * LY + j) * 2 + __builtin_amdgcn_readfirstlane(xr[0 * LY + j])) * 256;
        const float* T1 = g_Tt + ((1 * LY + j) * 2 + __builtin_amdgcn_readfirstlane(xr[1 * LY + j])) * 256;
        const float* T2 = g_Tt + ((2 * LY + j) * 2 + __builtin_amdgcn_readfirstlane(xr[2 * LY + j])) * 256;
        const float* T3 = g_Tt + ((3 * LY + j) * 2 + __builtin_amdgcn_readfirstlane(xr[3 * LY + j])) * 256;
        const float* T4 = g_Tt + ((4 * LY + j) * 2 + __builtin_amdgcn_readfirstlane(xr[4 * LY + j])) * 256;
        const float* T5 = g_Tt + ((5 * LY + j) * 2 + __builtin_amdgcn_readfirstlane(xr[5 * LY + j])) * 256;
        fused_pair<0, true,  false>(env, T0, T1, tid); __syncthreads();
        fused_pair<2, false, false>(env, T2, T3, tid); __syncthreads();
        fused_pair<4, false, true >(env, T4, T5, tid); __syncthreads();
    }

    // ---- column 5: closed-form MPS chain + dot with env ----
    {
        const float* B0 = g_Tt + ((0 * LY + 5) * 2 + __builtin_amdgcn_readfirstlane(xr[0 * LY + 5])) * 256;
        const float* B1 = g_Tt + ((1 * LY + 5) * 2 + __builtin_amdgcn_readfirstlane(xr[1 * LY + 5])) * 256;
        const float* B2 = g_Tt + ((2 * LY + 5) * 2 + __builtin_amdgcn_readfirstlane(xr[2 * LY + 5])) * 256;
        const float* B3 = g_Tt + ((3 * LY + 5) * 2 + __builtin_amdgcn_readfirstlane(xr[3 * LY + 5])) * 256;
        const float* B4 = g_Tt + ((4 * LY + 5) * 2 + __builtin_amdgcn_readfirstlane(xr[4 * LY + 5])) * 256;
        const float* B5 = g_Tt + ((5 * LY + 5) * 2 + __builtin_amdgcn_readfirstlane(xr[5 * LY + 5])) * 256;
        // B_i(l)[u][d] = T[(u + 4l)][(d + 4*0)]  (r' = 0 for column 5)
        const int l2 = tid & 3, l3 = (tid >> 2) & 3, l4 = (tid >> 4) & 3, l5 = (tid >> 6) & 3;
        float w[4], w2[4];
        #pragma unroll
        for (int u = 0; u < 4; ++u) w[u] = B5[(u + 4 * l5) * 16];                  // d = 0
        #pragma unroll
        for (int u = 0; u < 4; ++u) { float acc = 0;
            #pragma unroll
            for (int d = 0; d < 4; ++d) acc = __builtin_fmaf(B4[(u + 4 * l4) * 16 + d], w[d], acc);
            w2[u] = acc; }
        #pragma unroll
        for (int u = 0; u < 4; ++u) { float acc = 0;
            #pragma unroll
            for (int d = 0; d < 4; ++d) acc = __builtin_fmaf(B3[(u + 4 * l3) * 16 + d], w2[d], acc);
            w[u] = acc; }
        #pragma unroll
        for (int u = 0; u < 4; ++u) { float acc = 0;
            #pragma unroll
            for (int d = 0; d < 4; ++d) acc = __builtin_fmaf(B2[(u + 4 * l2) * 16 + d], w[d], acc);
            w2[u] = acc; }
        float partial = 0.f;
        #pragma unroll
        for (int l1 = 0; l1 < 4; ++l1) {
            float u1[4];
            #pragma unroll
            for (int u = 0; u < 4; ++u) { float acc = 0;
                #pragma unroll
                for (int d = 0; d < 4; ++d) acc = __builtin_fmaf(B1[(u + 4 * l1) * 16 + d], w2[d], acc);
                u1[u] = acc; }
            #pragma unroll
            for (int l0 = 0; l0 < 4; ++l0) {
                float wv = 0.f;
                #pragma unroll
                for (int d = 0; d < 4; ++d) wv = __builtin_fmaf(B0[(4 * l0) * 16 + d], u1[d], wv);
                partial = __builtin_fmaf(env[swz(4 * (l0 + 4 * l1 + 16 * tid))], wv, partial);
            }
        }
        #pragma unroll
        for (int off = 32; off; off >>= 1) partial += __shfl_down(partial, off);
        __syncthreads();                       // all env reads done before reuse
        if ((tid & 63) == 0) env[tid >> 6] = partial;
        __syncthreads();
        if (tid == 0) out[b] = env[0] + env[1] + env[2] + env[3];
    }
}

extern "C" void kernel_launch(void* const* d_in, const int* in_sizes, int n_in,
                              void* d_out, int out_size, void* d_ws, size_t ws_size,
                              hipStream_t stream) {
    const int* x = (const int*)d_in[0];
    const float* peps = (const float*)d_in[1];
    float* out = (float*)d_out;

    build_T_kernel<<<(TSZ + 255) / 256, 256, 0, stream>>>(peps);
    peps_amp_kernel<<<out_size, 256, 0, stream>>>(x, out);
}